// Round 2
// baseline (364.874 us; speedup 1.0000x reference)
//
#include <hip/hip_runtime.h>
#include <hip/hip_bf16.h>
#include <cstdint>

// KANLinear fused as ONE bf16 GEMM, K = 1024*8 (spline basis) + 1024 (silu) = 9216.
//   A[b, 8i+k]   = basis_k(x[b,i])   (only 4 of 8 nonzero; closed-form uniform cubic)
//   A[b, 8192+i] = silu(x[b,i])
//   W[o, 8i+k]   = spline_weight[o,i,k]  (already contiguous in this layout)
//   W[o, 8192+i] = base_weight[o,i]
// out = A @ W^T  (M=8192, N=1024, K=9216), fp32 in/out, bf16 MFMA internal.

typedef short s16x8 __attribute__((ext_vector_type(8)));   // 8 bf16 in 4 VGPRs
typedef float f32x4 __attribute__((ext_vector_type(4)));

#define GK 9216
#define GN 1024
#define GI 1024

__device__ __forceinline__ void cp16(const __hip_bfloat16* g, __hip_bfloat16* l) {
  // async global->LDS, 16 B/lane; LDS dest is wave-uniform base + lane*16 (guide §5)
  __builtin_amdgcn_global_load_lds((const __attribute__((address_space(1))) void*)g,
                                   (__attribute__((address_space(3))) void*)l, 16, 0, 0);
}

// --- basis helper: window start jj in [0,4], 4 uniform-cubic weights -------
__device__ __forceinline__ void basis4(float xv, int& jj, float& w0, float& w1,
                                       float& w2, float& w3) {
  float t = fminf(1.f, fmaxf(-1.f, xv));
  float us = (t + 1.f) * 2.5f;          // (t - grid[3]) / h, grid[3] = -1, h = 0.4
  int j = (int)us;                      // us >= 0 so trunc == floor
  if (j > 4) j = 4;                     // t == 1.0 edge: matches reference exactly
  float u = us - (float)j;
  float u2 = u * u, u3 = u2 * u;
  float om = 1.f - u;
  jj = j;
  w0 = om * om * om * (1.f / 6.f);
  w1 = (3.f * u3 - 6.f * u2 + 4.f) * (1.f / 6.f);
  w2 = (-3.f * u3 + 3.f * u2 + 3.f * u + 1.f) * (1.f / 6.f);
  w3 = u3 * (1.f / 6.f);
}

// --- kernel 1: weight repack fp32 -> bf16, (O=1024 rows of 9216) -----------
__global__ void kan_repack(const float* __restrict__ baseW,
                           const float* __restrict__ splineW,
                           __hip_bfloat16* __restrict__ W2) {
  int c = blockIdx.x * 256 + threadIdx.x;  // 0..9215 (grid.x = 36)
  int o = blockIdx.y;
  float v = (c < 8192) ? splineW[(size_t)o * 8192 + c]
                       : baseW[(size_t)o * GI + (c - 8192)];
  W2[(size_t)o * GK + c] = __float2bfloat16(v);
}

// --- kernel 2: activation prep: fp32 x -> bf16 [basis(8) | silu] -----------
__global__ void kan_prep(const float* __restrict__ x,
                         __hip_bfloat16* __restrict__ A, int rows) {
  int idx = blockIdx.x * 256 + threadIdx.x;  // grid exact: rows*1024 threads
  if (idx >= rows * GI) return;
  int b = idx >> 10, i = idx & 1023;
  float xv = x[idx];

  float sl = xv / (1.f + __expf(-xv));  // silu (unclipped x, matches reference)
  A[(size_t)b * GK + 8192 + i] = __float2bfloat16(sl);

  int jj; float w0, w1, w2, w3;
  basis4(xv, jj, w0, w1, w2, w3);
  union { __hip_bfloat16 h[8]; uint4 v; } pk;
#pragma unroll
  for (int s = 0; s < 8; ++s) {
    int d = s - jj;
    float val = (d == 0) ? w0 : (d == 1) ? w1 : (d == 2) ? w2 : (d == 3) ? w3 : 0.f;
    pk.h[s] = __float2bfloat16(val);
  }
  *(uint4*)(A + (size_t)b * GK + (size_t)i * 8) = pk.v;  // 16 B coalesced
}

// --- kernel 3: m97-style bf16 GEMM, B^T layout, 128x128x32 tile ------------
__global__ __launch_bounds__(256) void kan_gemm(
    const __hip_bfloat16* __restrict__ A,   // (Mchunk, 9216) bf16
    const __hip_bfloat16* __restrict__ B,   // (1024, 9216) bf16 = W^T rows
    float* __restrict__ C) {                // (Mchunk, 1024) fp32
  __shared__ __align__(16) __hip_bfloat16 As[128 * 32];
  __shared__ __align__(16) __hip_bfloat16 Bs[128 * 32];
  const int tid = threadIdx.x;
  const int lane = tid & 63;
  const int wave = tid >> 6;
  const int wm = wave >> 1, wn = wave & 1;  // 2x2 waves, 64x64 each
  const int blockRow = blockIdx.y * 128;
  const int blockCol = blockIdx.x * 128;

  // staging: lane copies 16 B = 8 bf16 of row (tid>>2), col chunk (tid&3)
  const __hip_bfloat16* aPtr = A + (size_t)(blockRow + (tid >> 2)) * GK + (tid & 3) * 8;
  const __hip_bfloat16* bPtr = B + (size_t)(blockCol + (tid >> 2)) * GK + (tid & 3) * 8;
  __hip_bfloat16* ldsA = As + wave * 512;   // wave-uniform; HW adds lane*16 B
  __hip_bfloat16* ldsB = Bs + wave * 512;

  f32x4 acc[4][4] = {};

  const int q = lane >> 4;       // k-quad
  const int r16 = lane & 15;     // row within 16x16 frag
  const s16x8* Af = (const s16x8*)As;
  const s16x8* Bf = (const s16x8*)Bs;
  const int aRow = wm * 64 + r16;
  const int bRow = wn * 64 + r16;

  for (int kt = 0; kt < GK / 32; ++kt) {
    cp16(aPtr, ldsA);                           // rows 0..63
    cp16(aPtr + (size_t)64 * GK, ldsA + 2048);  // rows 64..127 (+4096 B in LDS)
    cp16(bPtr, ldsB);
    cp16(bPtr + (size_t)64 * GK, ldsB + 2048);
    aPtr += 32; bPtr += 32;
    __syncthreads();   // drains vmcnt(0) -> tiles visible

    s16x8 af[4], bfg[4];
#pragma unroll
    for (int tm = 0; tm < 4; ++tm) af[tm] = Af[(aRow + tm * 16) * 4 + q];
#pragma unroll
    for (int tn = 0; tn < 4; ++tn) bfg[tn] = Bf[(bRow + tn * 16) * 4 + q];
#pragma unroll
    for (int tm = 0; tm < 4; ++tm)
#pragma unroll
      for (int tn = 0; tn < 4; ++tn)
        acc[tm][tn] = __builtin_amdgcn_mfma_f32_16x16x32_bf16(
            af[tm], bfg[tn], acc[tm][tn], 0, 0, 0);
    __syncthreads();   // all waves done reading before next overwrite
  }

  // C/D layout: col = lane&15, row = (lane>>4)*4 + reg  [m89-verified]
  const int cRow0 = blockRow + wm * 64 + q * 4;
  const int cCol0 = blockCol + wn * 64 + r16;
#pragma unroll
  for (int tm = 0; tm < 4; ++tm)
#pragma unroll
    for (int tn = 0; tn < 4; ++tn) {
      int col = cCol0 + tn * 16;
#pragma unroll
      for (int r = 0; r < 4; ++r) {
        int row = cRow0 + tm * 16 + r;
        C[(size_t)row * GN + col] = acc[tm][tn][r];
      }
    }
}

// --- emergency fallback if ws_size is too small: naive, correct, slow ------
__global__ void kan_naive(const float* __restrict__ x,
                          const float* __restrict__ bw,
                          const float* __restrict__ sw,
                          float* __restrict__ out) {
  int o = blockIdx.x * 256 + threadIdx.x;  // grid.x = 4
  int b = blockIdx.y;
  float acc = 0.f;
  for (int i = 0; i < GI; ++i) {
    float xv = x[(size_t)b * GI + i];
    float sl = xv / (1.f + __expf(-xv));
    acc += sl * bw[(size_t)o * GI + i];
    int jj; float w0, w1, w2, w3;
    basis4(xv, jj, w0, w1, w2, w3);
    const float* swr = sw + ((size_t)o * GI + i) * 8 + jj;
    acc += w0 * swr[0] + w1 * swr[1] + w2 * swr[2] + w3 * swr[3];
  }
  out[(size_t)b * GN + o] = acc;
}

extern "C" void kernel_launch(void* const* d_in, const int* in_sizes, int n_in,
                              void* d_out, int out_size, void* d_ws, size_t ws_size,
                              hipStream_t stream) {
  const float* x  = (const float*)d_in[0];   // (8192, 1024) fp32
  const float* bw = (const float*)d_in[1];   // (1024, 1024) fp32
  const float* sw = (const float*)d_in[2];   // (1024, 1024, 8) fp32
  float* out = (float*)d_out;                // (8192, 1024) fp32

  const int M = 8192;
  const size_t wBytes = (size_t)GK * GN * 2;            // 18.9 MB repacked weights
  const size_t rowBytes = (size_t)GK * 2;               // 18432 B per A row
  const size_t minNeed = wBytes + 128 * rowBytes;

  if (ws_size < minNeed) {  // ws too small for the GEMM path
    kan_naive<<<dim3(GN / 256, M), 256, 0, stream>>>(x, bw, sw, out);
    return;
  }

  __hip_bfloat16* W2 = (__hip_bfloat16*)d_ws;
  __hip_bfloat16* Abuf = W2 + (size_t)GK * GN;          // 16B-aligned (wBytes%16==0)

  size_t availRows = (ws_size - wBytes) / rowBytes;
  int rowsPerChunk = (int)(availRows > (size_t)M ? (size_t)M : availRows);
  rowsPerChunk &= ~127;                                  // multiple of BM=128

  kan_repack<<<dim3(GK / 256, GN), 256, 0, stream>>>(bw, sw, W2);

  for (int r0 = 0; r0 < M; r0 += rowsPerChunk) {
    int rows = (M - r0 < rowsPerChunk) ? (M - r0) : rowsPerChunk;
    kan_prep<<<rows * (GI / 256), 256, 0, stream>>>(x + (size_t)r0 * GI, Abuf, rows);
    kan_gemm<<<dim3(GN / 128, rows / 128), 256, 0, stream>>>(
        Abuf, W2, out + (size_t)r0 * GN);
  }
}

// Round 3
// 340.291 us; speedup vs baseline: 1.0722x; 1.0722x over previous
//
#include <hip/hip_runtime.h>
#include <hip/hip_bf16.h>
#include <cstdint>

// KANLinear fused as ONE bf16 GEMM, K = 1024*8 (spline basis) + 1024 (silu) = 9216.
//   A[b, 8i+k]   = basis_k(x[b,i]);  A[b, 8192+i] = silu(x[b,i])
//   W[o, 8i+k]   = spline_weight[o,i,k];  W[o, 8192+i] = base_weight[o,i]
// out = A @ W^T  (M=8192, N=1024, K=9216), fp32 in/out, bf16 MFMA internal.
//
// R2: BK=64 as two side-by-side BK=32 LDS tiles (keeps cp16 lane-contiguity
// and the free 2-way ds_read pattern) -> barrier count 288->144, 32 MFMA/wave
// per drain. Grid is 512 blocks = 2 blocks/CU, so 32 KB LDS/block is free.

typedef short s16x8 __attribute__((ext_vector_type(8)));   // 8 bf16 in 4 VGPRs
typedef float f32x4 __attribute__((ext_vector_type(4)));

#define GK 9216
#define GN 1024
#define GI 1024

__device__ __forceinline__ void cp16(const __hip_bfloat16* g, __hip_bfloat16* l) {
  __builtin_amdgcn_global_load_lds((const __attribute__((address_space(1))) void*)g,
                                   (__attribute__((address_space(3))) void*)l, 16, 0, 0);
}

__device__ __forceinline__ void basis4(float xv, int& jj, float& w0, float& w1,
                                       float& w2, float& w3) {
  float t = fminf(1.f, fmaxf(-1.f, xv));
  float us = (t + 1.f) * 2.5f;          // (t - grid[3]) / h, grid[3]=-1, h=0.4
  int j = (int)us;
  if (j > 4) j = 4;                     // t==1.0 edge: matches reference exactly
  float u = us - (float)j;
  float u2 = u * u, u3 = u2 * u;
  float om = 1.f - u;
  jj = j;
  w0 = om * om * om * (1.f / 6.f);
  w1 = (3.f * u3 - 6.f * u2 + 4.f) * (1.f / 6.f);
  w2 = (-3.f * u3 + 3.f * u2 + 3.f * u + 1.f) * (1.f / 6.f);
  w3 = u3 * (1.f / 6.f);
}

// --- kernel 1: weight repack fp32 -> bf16 ----------------------------------
__global__ void kan_repack(const float* __restrict__ baseW,
                           const float* __restrict__ splineW,
                           __hip_bfloat16* __restrict__ W2) {
  int c = blockIdx.x * 256 + threadIdx.x;  // 0..9215 (grid.x = 36)
  int o = blockIdx.y;
  float v = (c < 8192) ? splineW[(size_t)o * 8192 + c]
                       : baseW[(size_t)o * GI + (c - 8192)];
  W2[(size_t)o * GK + c] = __float2bfloat16(v);
}

// --- kernel 2a: basis prep (16 B coalesced stores) -------------------------
__global__ void kan_prep_basis(const float* __restrict__ x,
                               __hip_bfloat16* __restrict__ A, int rows) {
  int idx = blockIdx.x * 256 + threadIdx.x;
  if (idx >= rows * GI) return;
  int b = idx >> 10, i = idx & 1023;
  float xv = x[idx];
  int jj; float w0, w1, w2, w3;
  basis4(xv, jj, w0, w1, w2, w3);
  union { __hip_bfloat16 h[8]; uint4 v; } pk;
#pragma unroll
  for (int s = 0; s < 8; ++s) {
    int d = s - jj;
    float val = (d == 0) ? w0 : (d == 1) ? w1 : (d == 2) ? w2 : (d == 3) ? w3 : 0.f;
    pk.h[s] = __float2bfloat16(val);
  }
  *(uint4*)(A + (size_t)b * GK + (size_t)i * 8) = pk.v;
}

// --- kernel 2b: silu prep, 8 elems/thread, 32 B reads + 16 B stores --------
__global__ void kan_prep_silu(const float* __restrict__ x,
                              __hip_bfloat16* __restrict__ A, int rows) {
  int idx = blockIdx.x * 256 + threadIdx.x;   // rows*128 threads
  if (idx >= rows * (GI / 8)) return;
  int b = idx >> 7, i8 = (idx & 127) * 8;
  const float4* xp = (const float4*)(x + (size_t)b * GI + i8);
  float4 x0 = xp[0], x1 = xp[1];
  float v[8] = {x0.x, x0.y, x0.z, x0.w, x1.x, x1.y, x1.z, x1.w};
  union { __hip_bfloat16 h[8]; uint4 u; } pk;
#pragma unroll
  for (int s = 0; s < 8; ++s)
    pk.h[s] = __float2bfloat16(v[s] / (1.f + __expf(-v[s])));
  *(uint4*)(A + (size_t)b * GK + 8192 + i8) = pk.u;
}

// --- kernel 3: bf16 GEMM, 128x128 tile, BK=64 via dual BK=32 buffers -------
__global__ __launch_bounds__(256) void kan_gemm(
    const __hip_bfloat16* __restrict__ A,   // (M, 9216) bf16
    const __hip_bfloat16* __restrict__ B,   // (1024, 9216) bf16
    float* __restrict__ C) {                // (M, 1024) fp32
  __shared__ __align__(16) __hip_bfloat16 As[2][128 * 32];
  __shared__ __align__(16) __hip_bfloat16 Bs[2][128 * 32];
  const int tid = threadIdx.x;
  const int lane = tid & 63;
  const int wave = tid >> 6;
  const int wm = wave >> 1, wn = wave & 1;   // 2x2 waves, 64x64 each
  const int blockRow = blockIdx.y * 128;
  const int blockCol = blockIdx.x * 128;

  // staging: lane copies 16 B of row (tid>>2), k-chunk (tid&3) within a BK=32 tile
  const __hip_bfloat16* aPtr = A + (size_t)(blockRow + (tid >> 2)) * GK + (tid & 3) * 8;
  const __hip_bfloat16* bPtr = B + (size_t)(blockCol + (tid >> 2)) * GK + (tid & 3) * 8;
  __hip_bfloat16* ldsA0 = As[0] + wave * 512;   // wave-uniform; HW adds lane*16 B
  __hip_bfloat16* ldsA1 = As[1] + wave * 512;
  __hip_bfloat16* ldsB0 = Bs[0] + wave * 512;
  __hip_bfloat16* ldsB1 = Bs[1] + wave * 512;

  f32x4 acc[4][4] = {};

  const int q = lane >> 4;       // k-quad
  const int r16 = lane & 15;
  const int aRow = wm * 64 + r16;
  const int bRow = wn * 64 + r16;

  for (int kt = 0; kt < GK / 64; ++kt) {        // 144 iters
    cp16(aPtr, ldsA0);                          // k 0..31, rows 0..63
    cp16(aPtr + (size_t)64 * GK, ldsA0 + 2048); // k 0..31, rows 64..127
    cp16(aPtr + 32, ldsA1);                     // k 32..63
    cp16(aPtr + 32 + (size_t)64 * GK, ldsA1 + 2048);
    cp16(bPtr, ldsB0);
    cp16(bPtr + (size_t)64 * GK, ldsB0 + 2048);
    cp16(bPtr + 32, ldsB1);
    cp16(bPtr + 32 + (size_t)64 * GK, ldsB1 + 2048);
    aPtr += 64; bPtr += 64;
    __syncthreads();   // drains vmcnt(0) -> all 4 tiles visible

#pragma unroll
    for (int s = 0; s < 2; ++s) {
      const s16x8* Af = (const s16x8*)As[s];
      const s16x8* Bf = (const s16x8*)Bs[s];
      s16x8 af[4], bfg[4];
#pragma unroll
      for (int tm = 0; tm < 4; ++tm) af[tm] = Af[(aRow + tm * 16) * 4 + q];
#pragma unroll
      for (int tn = 0; tn < 4; ++tn) bfg[tn] = Bf[(bRow + tn * 16) * 4 + q];
#pragma unroll
      for (int tm = 0; tm < 4; ++tm)
#pragma unroll
        for (int tn = 0; tn < 4; ++tn)
          acc[tm][tn] = __builtin_amdgcn_mfma_f32_16x16x32_bf16(
              af[tm], bfg[tn], acc[tm][tn], 0, 0, 0);
    }
    __syncthreads();   // all waves done reading before next overwrite
  }

  // C/D layout: col = lane&15, row = (lane>>4)*4 + reg  [m89-verified]
  const int cRow0 = blockRow + wm * 64 + q * 4;
  const int cCol0 = blockCol + wn * 64 + r16;
#pragma unroll
  for (int tm = 0; tm < 4; ++tm)
#pragma unroll
    for (int tn = 0; tn < 4; ++tn) {
      int col = cCol0 + tn * 16;
#pragma unroll
      for (int r = 0; r < 4; ++r) {
        int row = cRow0 + tm * 16 + r;
        C[(size_t)row * GN + col] = acc[tm][tn][r];
      }
    }
}

// --- emergency fallback if ws_size is too small ----------------------------
__global__ void kan_naive(const float* __restrict__ x,
                          const float* __restrict__ bw,
                          const float* __restrict__ sw,
                          float* __restrict__ out) {
  int o = blockIdx.x * 256 + threadIdx.x;
  int b = blockIdx.y;
  float acc = 0.f;
  for (int i = 0; i < GI; ++i) {
    float xv = x[(size_t)b * GI + i];
    float sl = xv / (1.f + __expf(-xv));
    acc += sl * bw[(size_t)o * GI + i];
    int jj; float w0, w1, w2, w3;
    basis4(xv, jj, w0, w1, w2, w3);
    const float* swr = sw + ((size_t)o * GI + i) * 8 + jj;
    acc += w0 * swr[0] + w1 * swr[1] + w2 * swr[2] + w3 * swr[3];
  }
  out[(size_t)b * GN + o] = acc;
}

extern "C" void kernel_launch(void* const* d_in, const int* in_sizes, int n_in,
                              void* d_out, int out_size, void* d_ws, size_t ws_size,
                              hipStream_t stream) {
  const float* x  = (const float*)d_in[0];   // (8192, 1024) fp32
  const float* bw = (const float*)d_in[1];   // (1024, 1024) fp32
  const float* sw = (const float*)d_in[2];   // (1024, 1024, 8) fp32
  float* out = (float*)d_out;                // (8192, 1024) fp32

  const int M = 8192;
  const size_t wBytes = (size_t)GK * GN * 2;            // 18.9 MB repacked weights
  const size_t rowBytes = (size_t)GK * 2;               // 18432 B per A row
  const size_t minNeed = wBytes + 128 * rowBytes;

  if (ws_size < minNeed) {
    kan_naive<<<dim3(GN / 256, M), 256, 0, stream>>>(x, bw, sw, out);
    return;
  }

  __hip_bfloat16* W2 = (__hip_bfloat16*)d_ws;
  __hip_bfloat16* Abuf = W2 + (size_t)GK * GN;          // 16B-aligned

  size_t availRows = (ws_size - wBytes) / rowBytes;
  int rowsPerChunk = (int)(availRows > (size_t)M ? (size_t)M : availRows);
  rowsPerChunk &= ~127;

  kan_repack<<<dim3(GK / 256, GN), 256, 0, stream>>>(bw, sw, W2);

  for (int r0 = 0; r0 < M; r0 += rowsPerChunk) {
    int rows = (M - r0 < rowsPerChunk) ? (M - r0) : rowsPerChunk;
    kan_prep_basis<<<rows * (GI / 256), 256, 0, stream>>>(x + (size_t)r0 * GI, Abuf, rows);
    kan_prep_silu<<<rows * (GI / 8) / 256, 256, 0, stream>>>(x + (size_t)r0 * GI, Abuf, rows);
    kan_gemm<<<dim3(GN / 128, rows / 128), 256, 0, stream>>>(
        Abuf, W2, out + (size_t)r0 * GN);
  }
}

// Round 4
// 319.361 us; speedup vs baseline: 1.1425x; 1.0655x over previous
//
#include <hip/hip_runtime.h>
#include <hip/hip_bf16.h>
#include <cstdint>

// KANLinear fused as ONE bf16 GEMM, K = 1024*8 (spline basis) + 1024 (silu) = 9216.
//   A[b, 8i+k]   = basis_k(x[b,i]);  A[b, 8192+i] = silu(x[b,i])
//   W[o, 8i+k]   = spline_weight[o,i,k];  W[o, 8192+i] = base_weight[o,i]
// out = A @ W^T  (M=8192, N=1024, K=9216), fp32 in/out, bf16 MFMA internal.
//
// R3: (a) single fused prep dispatch (repack 32B-load/16B-store vectorized);
//     (b) XCD swizzle in GEMM: XCD = linear%8 hosts rowBands [8X,8X+8) x all
//         colBands -> the 8 readers of each A k-slice share one L2.
//         Expect FETCH 585 MB -> ~250 MB.

typedef short s16x8 __attribute__((ext_vector_type(8)));   // 8 bf16 in 4 VGPRs
typedef float f32x4 __attribute__((ext_vector_type(4)));

#define GK 9216
#define GN 1024
#define GI 1024
#define GM 8192

// fused-prep block partition (256 threads each)
#define RP_BLK 4608    // repack: 1024*9216/8 threads
#define BS_BLK 32768   // basis : 8192*1024 threads
#define SL_BLK 4096    // silu  : 8192*128 threads

__device__ __forceinline__ void cp16(const __hip_bfloat16* g, __hip_bfloat16* l) {
  __builtin_amdgcn_global_load_lds((const __attribute__((address_space(1))) void*)g,
                                   (__attribute__((address_space(3))) void*)l, 16, 0, 0);
}

__device__ __forceinline__ void basis4(float xv, int& jj, float& w0, float& w1,
                                       float& w2, float& w3) {
  float t = fminf(1.f, fmaxf(-1.f, xv));
  float us = (t + 1.f) * 2.5f;          // (t - grid[3]) / h, grid[3]=-1, h=0.4
  int j = (int)us;
  if (j > 4) j = 4;                     // t==1.0 edge: matches reference exactly
  float u = us - (float)j;
  float u2 = u * u, u3 = u2 * u;
  float om = 1.f - u;
  jj = j;
  w0 = om * om * om * (1.f / 6.f);
  w1 = (3.f * u3 - 6.f * u2 + 4.f) * (1.f / 6.f);
  w2 = (-3.f * u3 + 3.f * u2 + 3.f * u + 1.f) * (1.f / 6.f);
  w3 = u3 * (1.f / 6.f);
}

// --- ONE dispatch: weight repack + basis + silu ----------------------------
__global__ void kan_prep_all(const float* __restrict__ x,
                             const float* __restrict__ baseW,
                             const float* __restrict__ splineW,
                             __hip_bfloat16* __restrict__ W2,
                             __hip_bfloat16* __restrict__ A) {
  int bid = blockIdx.x;
  if (bid < RP_BLK) {
    // repack: thread handles 8 consecutive cols (32 B fp32 in, 16 B bf16 out)
    int t = bid * 256 + threadIdx.x;          // [0, 1024*1152)
    int o = t / 1152;                          // 1152 = 9216/8 chunks per row
    int c = (t - o * 1152) * 8;
    const float* src = (c < 8192) ? (splineW + (size_t)o * 8192 + c)
                                  : (baseW + (size_t)o * GI + (c - 8192));
    float4 v0 = ((const float4*)src)[0];
    float4 v1 = ((const float4*)src)[1];
    float v[8] = {v0.x, v0.y, v0.z, v0.w, v1.x, v1.y, v1.z, v1.w};
    union { __hip_bfloat16 h[8]; uint4 u; } pk;
#pragma unroll
    for (int s = 0; s < 8; ++s) pk.h[s] = __float2bfloat16(v[s]);
    *(uint4*)(W2 + (size_t)o * GK + c) = pk.u;
  } else if (bid < RP_BLK + BS_BLK) {
    // basis: thread per x-value, 16 B coalesced store
    int t = (bid - RP_BLK) * 256 + threadIdx.x;   // [0, 8192*1024)
    int b = t >> 10, i = t & 1023;
    float xv = x[t];
    int jj; float w0, w1, w2, w3;
    basis4(xv, jj, w0, w1, w2, w3);
    union { __hip_bfloat16 h[8]; uint4 v; } pk;
#pragma unroll
    for (int s = 0; s < 8; ++s) {
      int d = s - jj;
      float val = (d == 0) ? w0 : (d == 1) ? w1 : (d == 2) ? w2 : (d == 3) ? w3 : 0.f;
      pk.h[s] = __float2bfloat16(val);
    }
    *(uint4*)(A + (size_t)b * GK + (size_t)i * 8) = pk.v;
  } else {
    // silu: thread per 8 x-values (32 B in, 16 B out)
    int t = (bid - RP_BLK - BS_BLK) * 256 + threadIdx.x;  // [0, 8192*128)
    int b = t >> 7, i8 = (t & 127) * 8;
    const float4* xp = (const float4*)(x + (size_t)b * GI + i8);
    float4 x0 = xp[0], x1 = xp[1];
    float v[8] = {x0.x, x0.y, x0.z, x0.w, x1.x, x1.y, x1.z, x1.w};
    union { __hip_bfloat16 h[8]; uint4 u; } pk;
#pragma unroll
    for (int s = 0; s < 8; ++s)
      pk.h[s] = __float2bfloat16(v[s] / (1.f + __expf(-v[s])));
    *(uint4*)(A + (size_t)b * GK + 8192 + i8) = pk.u;
  }
}

// --- GEMM: 128x128 tile, BK=64 dual BK=32 buffers, XCD-swizzled ------------
__global__ __launch_bounds__(256) void kan_gemm(
    const __hip_bfloat16* __restrict__ A,   // (8192, 9216) bf16
    const __hip_bfloat16* __restrict__ B,   // (1024, 9216) bf16
    float* __restrict__ C) {                // (8192, 1024) fp32
  __shared__ __align__(16) __hip_bfloat16 As[2][128 * 32];
  __shared__ __align__(16) __hip_bfloat16 Bs[2][128 * 32];
  const int tid = threadIdx.x;
  const int lane = tid & 63;
  const int wave = tid >> 6;
  const int wm = wave >> 1, wn = wave & 1;   // 2x2 waves, 64x64 each

  // XCD swizzle: linear%8 (the XCD, heuristically) picks a group of 8
  // consecutive rowBands; colBand = linear/64. Bijective on 512 blocks.
  const int linear = blockIdx.y * 8 + blockIdx.x;
  const int rowBand = (linear & 7) * 8 + ((linear >> 3) & 7);
  const int colBand = linear >> 6;
  const int blockRow = rowBand * 128;
  const int blockCol = colBand * 128;

  const __hip_bfloat16* aPtr = A + (size_t)(blockRow + (tid >> 2)) * GK + (tid & 3) * 8;
  const __hip_bfloat16* bPtr = B + (size_t)(blockCol + (tid >> 2)) * GK + (tid & 3) * 8;
  __hip_bfloat16* ldsA0 = As[0] + wave * 512;   // wave-uniform; HW adds lane*16 B
  __hip_bfloat16* ldsA1 = As[1] + wave * 512;
  __hip_bfloat16* ldsB0 = Bs[0] + wave * 512;
  __hip_bfloat16* ldsB1 = Bs[1] + wave * 512;

  f32x4 acc[4][4] = {};

  const int q = lane >> 4;       // k-quad
  const int r16 = lane & 15;
  const int aRow = wm * 64 + r16;
  const int bRow = wn * 64 + r16;

  for (int kt = 0; kt < GK / 64; ++kt) {        // 144 iters
    cp16(aPtr, ldsA0);                          // k 0..31, rows 0..63
    cp16(aPtr + (size_t)64 * GK, ldsA0 + 2048); // k 0..31, rows 64..127
    cp16(aPtr + 32, ldsA1);                     // k 32..63
    cp16(aPtr + 32 + (size_t)64 * GK, ldsA1 + 2048);
    cp16(bPtr, ldsB0);
    cp16(bPtr + (size_t)64 * GK, ldsB0 + 2048);
    cp16(bPtr + 32, ldsB1);
    cp16(bPtr + 32 + (size_t)64 * GK, ldsB1 + 2048);
    aPtr += 64; bPtr += 64;
    __syncthreads();   // drains vmcnt(0) -> all 4 tiles visible

#pragma unroll
    for (int s = 0; s < 2; ++s) {
      const s16x8* Af = (const s16x8*)As[s];
      const s16x8* Bf = (const s16x8*)Bs[s];
      s16x8 af[4], bfg[4];
#pragma unroll
      for (int tm = 0; tm < 4; ++tm) af[tm] = Af[(aRow + tm * 16) * 4 + q];
#pragma unroll
      for (int tn = 0; tn < 4; ++tn) bfg[tn] = Bf[(bRow + tn * 16) * 4 + q];
#pragma unroll
      for (int tm = 0; tm < 4; ++tm)
#pragma unroll
        for (int tn = 0; tn < 4; ++tn)
          acc[tm][tn] = __builtin_amdgcn_mfma_f32_16x16x32_bf16(
              af[tm], bfg[tn], acc[tm][tn], 0, 0, 0);
    }
    __syncthreads();   // all waves done reading before next overwrite
  }

  // C/D layout: col = lane&15, row = (lane>>4)*4 + reg  [m89-verified]
  const int cRow0 = blockRow + wm * 64 + q * 4;
  const int cCol0 = blockCol + wn * 64 + r16;
#pragma unroll
  for (int tm = 0; tm < 4; ++tm)
#pragma unroll
    for (int tn = 0; tn < 4; ++tn) {
      int col = cCol0 + tn * 16;
#pragma unroll
      for (int r = 0; r < 4; ++r) {
        int row = cRow0 + tm * 16 + r;
        C[(size_t)row * GN + col] = acc[tm][tn][r];
      }
    }
}

// --- emergency fallback if ws_size is too small ----------------------------
__global__ void kan_naive(const float* __restrict__ x,
                          const float* __restrict__ bw,
                          const float* __restrict__ sw,
                          float* __restrict__ out) {
  int o = blockIdx.x * 256 + threadIdx.x;
  int b = blockIdx.y;
  float acc = 0.f;
  for (int i = 0; i < GI; ++i) {
    float xv = x[(size_t)b * GI + i];
    float sl = xv / (1.f + __expf(-xv));
    acc += sl * bw[(size_t)o * GI + i];
    int jj; float w0, w1, w2, w3;
    basis4(xv, jj, w0, w1, w2, w3);
    const float* swr = sw + ((size_t)o * GI + i) * 8 + jj;
    acc += w0 * swr[0] + w1 * swr[1] + w2 * swr[2] + w3 * swr[3];
  }
  out[(size_t)b * GN + o] = acc;
}

extern "C" void kernel_launch(void* const* d_in, const int* in_sizes, int n_in,
                              void* d_out, int out_size, void* d_ws, size_t ws_size,
                              hipStream_t stream) {
  const float* x  = (const float*)d_in[0];   // (8192, 1024) fp32
  const float* bw = (const float*)d_in[1];   // (1024, 1024) fp32
  const float* sw = (const float*)d_in[2];   // (1024, 1024, 8) fp32
  float* out = (float*)d_out;                // (8192, 1024) fp32

  const size_t wBytes = (size_t)GK * GN * 2;   // 18.9 MB repacked weights
  const size_t aBytes = (size_t)GM * GK * 2;   // 151 MB activations
  if (ws_size < wBytes + aBytes) {
    kan_naive<<<dim3(GN / 256, GM), 256, 0, stream>>>(x, bw, sw, out);
    return;
  }

  __hip_bfloat16* W2 = (__hip_bfloat16*)d_ws;
  __hip_bfloat16* Abuf = W2 + (size_t)GK * GN;   // 16B-aligned

  kan_prep_all<<<RP_BLK + BS_BLK + SL_BLK, 256, 0, stream>>>(x, bw, sw, W2, Abuf);
  kan_gemm<<<dim3(GN / 128, GM / 128), 256, 0, stream>>>(Abuf, W2, out);
}

// Round 5
// 290.395 us; speedup vs baseline: 1.2565x; 1.0997x over previous
//
#include <hip/hip_runtime.h>
#include <hip/hip_bf16.h>
#include <cstdint>

// KANLinear fused as ONE bf16 GEMM, K = 1024*8 (spline basis) + 1024 (silu) = 9216.
//   A[b, 8i+k]   = basis_k(x[b,i]);  A[b, 8192+i] = silu(x[b,i])
//   W[o, 8i+k]   = spline_weight[o,i,k];  W[o, 8192+i] = base_weight[o,i]
// out = A @ W^T  (M=8192, N=1024, K=9216), fp32 in/out, bf16 MFMA internal.
//
// R4: prep rewritten union-free (mixed-size union pack suspected of defeating
// SROA -> scratch round-trips). Basis pack = uint64 bit-pack + guarded 128-bit
// shift by 16*jj. Silu fused into the same thread (x read once). GEMM kept:
// it is at the m97-structure plateau (872 TF, FETCH ~= ideal after XCD swizzle).

typedef short s16x8 __attribute__((ext_vector_type(8)));   // 8 bf16 in 4 VGPRs
typedef float f32x4 __attribute__((ext_vector_type(4)));

#define GK 9216
#define GN 1024
#define GI 1024
#define GM 8192

#define BS_BLK 32768   // basis+silu: 8192*1024 threads (1 per x)
#define RP_BLK 4608    // repack   : 1024*1152 threads (8 cols each)

__device__ __forceinline__ void cp16(const __hip_bfloat16* g, __hip_bfloat16* l) {
  __builtin_amdgcn_global_load_lds((const __attribute__((address_space(1))) void*)g,
                                   (__attribute__((address_space(3))) void*)l, 16, 0, 0);
}

__device__ __forceinline__ uint32_t bfbits(float f) {   // RTNE bf16 bits, SSA only
  __hip_bfloat16 h = __float2bfloat16(f);
  unsigned short us;
  __builtin_memcpy(&us, &h, 2);
  return (uint32_t)us;
}

__device__ __forceinline__ void basis4(float xv, int& jj, float& w0, float& w1,
                                       float& w2, float& w3) {
  float t = fminf(1.f, fmaxf(-1.f, xv));
  float us = (t + 1.f) * 2.5f;          // (t - grid[3]) / h, grid[3]=-1, h=0.4
  int j = (int)us;
  if (j > 4) j = 4;                     // t==1.0 edge: matches reference exactly
  float u = us - (float)j;
  float u2 = u * u, u3 = u2 * u;
  float om = 1.f - u;
  jj = j;
  w0 = om * om * om * (1.f / 6.f);
  w1 = (3.f * u3 - 6.f * u2 + 4.f) * (1.f / 6.f);
  w2 = (-3.f * u3 + 3.f * u2 + 3.f * u + 1.f) * (1.f / 6.f);
  w3 = u3 * (1.f / 6.f);
}

// --- ONE dispatch: basis+silu (1 thread/x) + weight repack -----------------
__global__ void kan_prep_all(const float* __restrict__ x,
                             const float* __restrict__ baseW,
                             const float* __restrict__ splineW,
                             __hip_bfloat16* __restrict__ W2,
                             __hip_bfloat16* __restrict__ A) {
  int bid = blockIdx.x;
  if (bid < BS_BLK) {
    int t = bid * 256 + threadIdx.x;        // [0, 8192*1024)
    int b = t >> 10, i = t & 1023;
    float xv = x[t];

    // silu -> A[b, 8192+i], 2 B coalesced store (wave covers 128 B)
    float sl = xv / (1.f + __expf(-xv));
    A[(size_t)b * GK + 8192 + i] = __float2bfloat16(sl);

    // basis -> A[b, 8i .. 8i+7]: pack 4 weights, shift into place, 16 B store
    int jj; float w0, w1, w2, w3;
    basis4(xv, jj, w0, w1, w2, w3);
    uint64_t W64 = (uint64_t)(bfbits(w0) | (bfbits(w1) << 16)) |
                   ((uint64_t)(bfbits(w2) | (bfbits(w3) << 16)) << 32);
    int sh = jj * 16;                                  // 0,16,32,48,64
    uint64_t lo = (jj < 4) ? (W64 << sh) : 0ull;       // guard UB at sh=64
    uint64_t hi = (jj == 0) ? 0ull : (W64 >> (64 - sh));
    uint4 pk;
    pk.x = (uint32_t)lo;  pk.y = (uint32_t)(lo >> 32);
    pk.z = (uint32_t)hi;  pk.w = (uint32_t)(hi >> 32);
    *(uint4*)(A + (size_t)b * GK + (size_t)i * 8) = pk;
  } else {
    // repack: thread handles 8 cols (32 B fp32 in, 16 B bf16 out), union-free
    int t = (bid - BS_BLK) * 256 + threadIdx.x;   // [0, 1024*1152)
    int o = t / 1152;
    int c = (t - o * 1152) * 8;
    const float* src = (c < 8192) ? (splineW + (size_t)o * 8192 + c)
                                  : (baseW + (size_t)o * GI + (c - 8192));
    float4 v0 = ((const float4*)src)[0];
    float4 v1 = ((const float4*)src)[1];
    uint4 pk;
    pk.x = bfbits(v0.x) | (bfbits(v0.y) << 16);
    pk.y = bfbits(v0.z) | (bfbits(v0.w) << 16);
    pk.z = bfbits(v1.x) | (bfbits(v1.y) << 16);
    pk.w = bfbits(v1.z) | (bfbits(v1.w) << 16);
    *(uint4*)(W2 + (size_t)o * GK + c) = pk;
  }
}

// --- GEMM: 128x128 tile, BK=64 dual BK=32 buffers, XCD-swizzled ------------
__global__ __launch_bounds__(256) void kan_gemm(
    const __hip_bfloat16* __restrict__ A,   // (8192, 9216) bf16
    const __hip_bfloat16* __restrict__ B,   // (1024, 9216) bf16
    float* __restrict__ C) {                // (8192, 1024) fp32
  __shared__ __align__(16) __hip_bfloat16 As[2][128 * 32];
  __shared__ __align__(16) __hip_bfloat16 Bs[2][128 * 32];
  const int tid = threadIdx.x;
  const int lane = tid & 63;
  const int wave = tid >> 6;
  const int wm = wave >> 1, wn = wave & 1;   // 2x2 waves, 64x64 each

  // XCD swizzle: linear%8 picks a group of 8 consecutive rowBands; the 8
  // same-XCD readers of an A k-slice share one L2. (R3: FETCH 599->147 MB)
  const int linear = blockIdx.y * 8 + blockIdx.x;
  const int rowBand = (linear & 7) * 8 + ((linear >> 3) & 7);
  const int colBand = linear >> 6;
  const int blockRow = rowBand * 128;
  const int blockCol = colBand * 128;

  const __hip_bfloat16* aPtr = A + (size_t)(blockRow + (tid >> 2)) * GK + (tid & 3) * 8;
  const __hip_bfloat16* bPtr = B + (size_t)(blockCol + (tid >> 2)) * GK + (tid & 3) * 8;
  __hip_bfloat16* ldsA0 = As[0] + wave * 512;   // wave-uniform; HW adds lane*16 B
  __hip_bfloat16* ldsA1 = As[1] + wave * 512;
  __hip_bfloat16* ldsB0 = Bs[0] + wave * 512;
  __hip_bfloat16* ldsB1 = Bs[1] + wave * 512;

  f32x4 acc[4][4] = {};

  const int q = lane >> 4;       // k-quad
  const int r16 = lane & 15;
  const int aRow = wm * 64 + r16;
  const int bRow = wn * 64 + r16;

  for (int kt = 0; kt < GK / 64; ++kt) {        // 144 iters
    cp16(aPtr, ldsA0);                          // k 0..31, rows 0..63
    cp16(aPtr + (size_t)64 * GK, ldsA0 + 2048); // k 0..31, rows 64..127
    cp16(aPtr + 32, ldsA1);                     // k 32..63
    cp16(aPtr + 32 + (size_t)64 * GK, ldsA1 + 2048);
    cp16(bPtr, ldsB0);
    cp16(bPtr + (size_t)64 * GK, ldsB0 + 2048);
    cp16(bPtr + 32, ldsB1);
    cp16(bPtr + 32 + (size_t)64 * GK, ldsB1 + 2048);
    aPtr += 64; bPtr += 64;
    __syncthreads();   // drains vmcnt(0) -> all 4 tiles visible

#pragma unroll
    for (int s = 0; s < 2; ++s) {
      const s16x8* Af = (const s16x8*)As[s];
      const s16x8* Bf = (const s16x8*)Bs[s];
      s16x8 af[4], bfg[4];
#pragma unroll
      for (int tm = 0; tm < 4; ++tm) af[tm] = Af[(aRow + tm * 16) * 4 + q];
#pragma unroll
      for (int tn = 0; tn < 4; ++tn) bfg[tn] = Bf[(bRow + tn * 16) * 4 + q];
#pragma unroll
      for (int tm = 0; tm < 4; ++tm)
#pragma unroll
        for (int tn = 0; tn < 4; ++tn)
          acc[tm][tn] = __builtin_amdgcn_mfma_f32_16x16x32_bf16(
              af[tm], bfg[tn], acc[tm][tn], 0, 0, 0);
    }
    __syncthreads();   // all waves done reading before next overwrite
  }

  // C/D layout: col = lane&15, row = (lane>>4)*4 + reg  [m89-verified]
  const int cRow0 = blockRow + wm * 64 + q * 4;
  const int cCol0 = blockCol + wn * 64 + r16;
#pragma unroll
  for (int tm = 0; tm < 4; ++tm)
#pragma unroll
    for (int tn = 0; tn < 4; ++tn) {
      int col = cCol0 + tn * 16;
#pragma unroll
      for (int r = 0; r < 4; ++r) {
        int row = cRow0 + tm * 16 + r;
        C[(size_t)row * GN + col] = acc[tm][tn][r];
      }
    }
}

// --- emergency fallback if ws_size is too small ----------------------------
__global__ void kan_naive(const float* __restrict__ x,
                          const float* __restrict__ bw,
                          const float* __restrict__ sw,
                          float* __restrict__ out) {
  int o = blockIdx.x * 256 + threadIdx.x;
  int b = blockIdx.y;
  float acc = 0.f;
  for (int i = 0; i < GI; ++i) {
    float xv = x[(size_t)b * GI + i];
    float sl = xv / (1.f + __expf(-xv));
    acc += sl * bw[(size_t)o * GI + i];
    int jj; float w0, w1, w2, w3;
    basis4(xv, jj, w0, w1, w2, w3);
    const float* swr = sw + ((size_t)o * GI + i) * 8 + jj;
    acc += w0 * swr[0] + w1 * swr[1] + w2 * swr[2] + w3 * swr[3];
  }
  out[(size_t)b * GN + o] = acc;
}

extern "C" void kernel_launch(void* const* d_in, const int* in_sizes, int n_in,
                              void* d_out, int out_size, void* d_ws, size_t ws_size,
                              hipStream_t stream) {
  const float* x  = (const float*)d_in[0];   // (8192, 1024) fp32
  const float* bw = (const float*)d_in[1];   // (1024, 1024) fp32
  const float* sw = (const float*)d_in[2];   // (1024, 1024, 8) fp32
  float* out = (float*)d_out;                // (8192, 1024) fp32

  const size_t wBytes = (size_t)GK * GN * 2;   // 18.9 MB repacked weights
  const size_t aBytes = (size_t)GM * GK * 2;   // 151 MB activations
  if (ws_size < wBytes + aBytes) {
    kan_naive<<<dim3(GN / 256, GM), 256, 0, stream>>>(x, bw, sw, out);
    return;
  }

  __hip_bfloat16* W2 = (__hip_bfloat16*)d_ws;
  __hip_bfloat16* Abuf = W2 + (size_t)GK * GN;   // 16B-aligned

  kan_prep_all<<<BS_BLK + RP_BLK, 256, 0, stream>>>(x, bw, sw, W2, Abuf);
  kan_gemm<<<dim3(GN / 128, GM / 128), 256, 0, stream>>>(Abuf, W2, out);
}